// Round 5
// baseline (1209.897 us; speedup 1.0000x reference)
//
#include <hip/hip_runtime.h>
#include <math.h>

#define NEGV -1e10f

typedef __bf16 bf16x8 __attribute__((ext_vector_type(8)));
typedef float f32x4 __attribute__((ext_vector_type(4)));
typedef unsigned short ushort;

__device__ __forceinline__ float fast_tanh(float x) {
    float e = __expf(2.0f * x);
    return fmaf(-2.f, __builtin_amdgcn_rcpf(e + 1.f), 1.f);
}
__device__ __forceinline__ float fast_sig(float x) {
    return __builtin_amdgcn_rcpf(1.f + __expf(-x));
}
__device__ __forceinline__ ushort f2bf(float x) {
    unsigned int b = __float_as_uint(x);
    b += 0x7fffu + ((b >> 16) & 1u);   // RNE
    return (ushort)(b >> 16);
}
// raw barrier: wait LDS only, leave global loads in flight (no vmcnt drain)
__device__ __forceinline__ void lds_barrier() {
    asm volatile("s_waitcnt lgkmcnt(0)\n\ts_barrier" ::: "memory");
}
// async 16B global -> LDS (dest = wave-uniform base + lane*16)
__device__ __forceinline__ void async16(void* l, const void* g) {
    __builtin_amdgcn_global_load_lds(
        (const __attribute__((address_space(1))) void*)g,
        (__attribute__((address_space(3))) void*)l,
        16, 0, 0);
}

// ---------------- fp32 -> bf16 cast (n % 8 == 0) ----------------
__global__ __launch_bounds__(256) void cast_bf16_kernel(
    const float* __restrict__ in, ushort* __restrict__ out, int n)
{
    int i = (blockIdx.x * 256 + threadIdx.x) * 8;
    if (i >= n) return;
    float4 a = *(const float4*)(in + i);
    float4 b = *(const float4*)(in + i + 4);
    uint4 o;
    o.x = (unsigned)f2bf(a.x) | ((unsigned)f2bf(a.y) << 16);
    o.y = (unsigned)f2bf(a.z) | ((unsigned)f2bf(a.w) << 16);
    o.z = (unsigned)f2bf(b.x) | ((unsigned)f2bf(b.y) << 16);
    o.w = (unsigned)f2bf(b.z) | ((unsigned)f2bf(b.w) << 16);
    *(uint4*)(out + i) = o;
}

// ---------------- pad-cast A: in[M][sk] f32 -> out[M][192] bf16 (zero pad) ----------------
__global__ __launch_bounds__(256) void pad_cast_a_kernel(
    const float* __restrict__ in, ushort* __restrict__ out, int M, int sk)
{
    int idx = blockIdx.x * 256 + threadIdx.x;       // row*24 + oct
    if (idx >= M * 24) return;
    int row = idx / 24, oct = idx - row * 24;
    int c0 = oct * 8;
    const float* src = in + (size_t)row * sk;
    ushort v[8];
    #pragma unroll
    for (int j = 0; j < 8; j++) {
        int c = c0 + j;
        v[j] = (c < 140) ? f2bf(src[c]) : (ushort)0;
    }
    *(uint4*)(out + (size_t)row * 192 + c0) = *(const uint4*)v;
}

// ---------------- pad-cast B: src rows (stride srcld, col offset soff) -> dst[Nout][192] ----------------
__global__ __launch_bounds__(96) void pad_cast_b_kernel(
    const float* __restrict__ src, ushort* __restrict__ dst,
    int Nsrc, int srcld, int soff)
{
    int row = blockIdx.x;
    int t = threadIdx.x;            // cols 2t, 2t+1
    float a = 0.f, b = 0.f;
    if (row < Nsrc) {
        const float* s = src + (size_t)row * srcld + soff;
        if (2 * t < 140) a = s[2 * t];
        if (2 * t + 1 < 140) b = s[2 * t + 1];
    }
    ((unsigned*)(dst + (size_t)row * 192))[t] =
        (unsigned)f2bf(a) | ((unsigned)f2bf(b) << 16);
}

__global__ __launch_bounds__(256) void pad_bias_kernel(
    const float* __restrict__ in, float* __restrict__ out, int n)
{
    int i = threadIdx.x;
    out[i] = (i < n) ? in[i] : 0.f;
}

// ---------------- MFMA GEMM: C = A[M,K]bf16 @ B[Ntiles*128,K]bf16^T (+bias) ----------------
// K % 64 == 0, M % 128 == 0. perm!=0: unit-major permuted store (ldc=256).
// LDS swizzle (T2, both-sides): phys_byte(r, cb) = r*128 + (cb ^ ((r&7)<<4)).
__global__ __launch_bounds__(256) void gemm_mfma_kernel(
    const ushort* __restrict__ A, const ushort* __restrict__ B,
    const float* __restrict__ bias, float* __restrict__ C,
    int M, int K, int ldc, int Nstore, int perm)
{
    __shared__ __align__(16) ushort ldsA[128 * 64];
    __shared__ __align__(16) ushort ldsB[128 * 64];
    const int tid = threadIdx.x;
    const int wv = tid >> 6, ln = tid & 63;
    const int bm = blockIdx.y * 128, bn = blockIdx.x * 128;
    const int r15 = ln & 15, r4 = ln >> 4;

    f32x4 acc[4][4] = {};

    for (int k0 = 0; k0 < K; k0 += 64) {
        #pragma unroll
        for (int c4 = 0; c4 < 4; c4++) {
            const int c = c4 * 4 + wv;
            const int s = c * 64 + ln;
            const int rt = s >> 3;
            const int ce = ((s & 7) ^ (rt & 7)) * 8;
            async16(&ldsA[c * 512], A + (size_t)(bm + rt) * K + k0 + ce);
            async16(&ldsB[c * 512], B + (size_t)(bn + rt) * K + k0 + ce);
        }
        __syncthreads();
        const int mr = (wv >> 1) * 64, nc = (wv & 1) * 64;
        #pragma unroll
        for (int kk = 0; kk < 2; kk++) {
            bf16x8 af[4], bfr[4];
            #pragma unroll
            for (int m = 0; m < 4; m++) {
                const int r = mr + m * 16 + r15;
                const int off = r * 128 + ((kk * 64 + r4 * 16) ^ ((r & 7) << 4));
                af[m] = *(const bf16x8*)((const char*)ldsA + off);
            }
            #pragma unroll
            for (int n = 0; n < 4; n++) {
                const int r = nc + n * 16 + r15;
                const int off = r * 128 + ((kk * 64 + r4 * 16) ^ ((r & 7) << 4));
                bfr[n] = *(const bf16x8*)((const char*)ldsB + off);
            }
            #pragma unroll
            for (int m = 0; m < 4; m++)
                #pragma unroll
                for (int n = 0; n < 4; n++)
                    acc[m][n] = __builtin_amdgcn_mfma_f32_16x16x32_bf16(
                        af[m], bfr[n], acc[m][n], 0, 0, 0);
        }
        __syncthreads();
    }
    const int mr = bm + (wv >> 1) * 64, nc = bn + (wv & 1) * 64;
    #pragma unroll
    for (int m = 0; m < 4; m++) {
        #pragma unroll
        for (int n = 0; n < 4; n++) {
            const int col = nc + n * 16 + r15;
            if (!perm && col >= Nstore) continue;
            const int cout = perm ? ((col & 63) * 4 + (col >> 6)) : col;
            const float bs = bias ? bias[col] : 0.f;
            #pragma unroll
            for (int r = 0; r < 4; r++) {
                const int row = mr + m * 16 + r4 * 4 + r;
                C[(size_t)row * ldc + cout] = acc[m][n][r] + bs;
            }
        }
    }
}

// ---------------- SIMT GEMM (small tail ops): C = A @ B^T (+bias) ----------------
__global__ __launch_bounds__(256) void gemm_bias_kernel(
    const float* __restrict__ A, const float* __restrict__ B,
    const float* __restrict__ bias, float* __restrict__ C,
    int M, int N, int K, int lda, int ldb, int ldc)
{
    __shared__ float As[16][68];
    __shared__ float Bs[16][68];
    const int tid = threadIdx.x;
    const int bm = blockIdx.y * 64;
    const int bn = blockIdx.x * 64;
    const int tx = tid & 15;
    const int ty = tid >> 4;
    const int lm = tid & 63;
    const int lk = (tid >> 6) << 2;
    float acc[4][4] = {};
    const int arow = bm + lm;
    const int brow = bn + lm;

    for (int k0 = 0; k0 < K; k0 += 16) {
        int k = k0 + lk;
        float4 av = make_float4(0.f, 0.f, 0.f, 0.f);
        float4 bv = make_float4(0.f, 0.f, 0.f, 0.f);
        if (arow < M) {
            if (k + 4 <= K) av = *(const float4*)(A + (size_t)arow * lda + k);
            else { float* p = (float*)&av;
                for (int i = 0; i < 4; i++) if (k + i < K) p[i] = A[(size_t)arow * lda + k + i]; }
        }
        if (brow < N) {
            if (k + 4 <= K) bv = *(const float4*)(B + (size_t)brow * ldb + k);
            else { float* p = (float*)&bv;
                for (int i = 0; i < 4; i++) if (k + i < K) p[i] = B[(size_t)brow * ldb + k + i]; }
        }
        As[lk + 0][lm] = av.x; As[lk + 1][lm] = av.y; As[lk + 2][lm] = av.z; As[lk + 3][lm] = av.w;
        Bs[lk + 0][lm] = bv.x; Bs[lk + 1][lm] = bv.y; Bs[lk + 2][lm] = bv.z; Bs[lk + 3][lm] = bv.w;
        __syncthreads();
        #pragma unroll
        for (int kk = 0; kk < 16; kk++) {
            float a[4], bb[4];
            #pragma unroll
            for (int i = 0; i < 4; i++) a[i] = As[kk][ty * 4 + i];
            #pragma unroll
            for (int j = 0; j < 4; j++) bb[j] = Bs[kk][tx * 4 + j];
            #pragma unroll
            for (int i = 0; i < 4; i++)
                #pragma unroll
                for (int j = 0; j < 4; j++)
                    acc[i][j] = fmaf(a[i], bb[j], acc[i][j]);
        }
        __syncthreads();
    }
    #pragma unroll
    for (int i = 0; i < 4; i++) {
        int row = bm + ty * 4 + i;
        if (row >= M) continue;
        #pragma unroll
        for (int j = 0; j < 4; j++) {
            int col = bn + tx * 4 + j;
            if (col < N) C[(size_t)row * ldc + col] = acc[i][j] + (bias ? bias[col] : 0.f);
        }
    }
}

// ------------- pre-pack Whh (8 matrices [256][64]) into MFMA B-frag order -------------
__global__ __launch_bounds__(256) void prepack_whh_kernel(
    const float* W0, const float* W1, const float* W2, const float* W3,
    const float* W4, const float* W5, const float* W6, const float* W7,
    ushort* frag)
{
    const float* Ws[8] = {W0, W1, W2, W3, W4, W5, W6, W7};
    const float* W = Ws[blockIdx.x];
    ushort* out = frag + (size_t)blockIdx.x * 16384;
    for (int r = 0; r < 8; r++) {
        int fl = threadIdx.x + 256 * r;            // 0..2047
        int tile = fl >> 7;
        int chunk = (fl >> 6) & 1;
        int lane = fl & 63;
        int row = tile * 16 + (lane & 15);
        int kb = chunk * 32 + 8 * (lane >> 4);
        #pragma unroll
        for (int j = 0; j < 8; j++)
            out[(size_t)fl * 8 + j] = f2bf(W[row * 64 + kb + j]);
    }
}

// ---------------- batched LSTM scan: 16 chains per block via MFMA M-dim ----------------
// A rows = chains (lane&15), B = Whh gate tiles; wave w owns units 16w..16w+15.
// Lane updates 1 unit x 4 chains (C rows (lane>>4)*4+r). h in LDS [chain][64] bf16,
// XOR-swizzled (byte ^ ((chain&7)<<4)). Per-chain predication for variable L.
__global__ __launch_bounds__(256) void lstm_scan_mfma16(
    const float* __restrict__ proj_f, const float* __restrict__ proj_b,
    const ushort* __restrict__ frag_f, const ushort* __restrict__ frag_b,
    const int* __restrict__ lengths,
    float* __restrict__ out, int T, int out_stride)
{
    const int dir = blockIdx.y;
    const int c0 = blockIdx.x * 16;
    const float* proj = dir ? proj_b : proj_f;
    const ushort* frag = dir ? frag_b : frag_f;
    const int tid = threadIdx.x;
    const int wv = tid >> 6, l = tid & 63;
    const int cq = l & 15, q = l >> 4;
    const int u = (wv << 4) + cq;

    bf16x8 bfr[4][2];
    #pragma unroll
    for (int G = 0; G < 4; G++)
        #pragma unroll
        for (int ch = 0; ch < 2; ch++)
            bfr[G][ch] = *reinterpret_cast<const bf16x8*>(
                frag + (((size_t)(4 * G + wv) * 2 + ch) * 64 + l) * 8);

    int Ls[4];
    #pragma unroll
    for (int r = 0; r < 4; r++) Ls[r] = lengths[c0 + 4 * q + r];
    int maxL = 0;
    for (int i = 0; i < 16; i++) maxL = max(maxL, lengths[c0 + i]);
    const int maxS = (maxL + 1) & ~1;

    __shared__ __align__(16) ushort hl[2][1024];
    for (int i = tid; i < 2048; i += 256) ((ushort*)hl)[i] = 0;
    __syncthreads();

    float cst[4] = {0.f, 0.f, 0.f, 0.f};
    const float* pp[4];
    float* op[4];
    const int pd = dir ? -256 : 256;
    const long od = dir ? -(long)out_stride : (long)out_stride;
    #pragma unroll
    for (int r = 0; r < 4; r++) {
        const int ch = c0 + 4 * q + r;
        const int t0 = dir ? (Ls[r] - 1) : 0;
        pp[r] = proj + (size_t)ch * T * 256 + (size_t)t0 * 256 + u * 4;
        op[r] = out + (size_t)ch * T * out_stride + (size_t)t0 * out_stride + dir * 64 + u;
    }
    float4 P0[4], P1[4];
    #pragma unroll
    for (int r = 0; r < 4; r++) {
        P0[r] = *(const float4*)pp[r];
        if (1 < Ls[r]) pp[r] += pd;
        P1[r] = *(const float4*)pp[r];
        if (2 < Ls[r]) pp[r] += pd;
    }

    const int ra = cq * 128 + ((q * 16) ^ ((cq & 7) << 4));

    auto body = [&](int s, float4 (&P)[4], int buf) {
        const char* hb = (const char*)hl[buf];
        bf16x8 a0 = *(const bf16x8*)(hb + ra);
        bf16x8 a1 = *(const bf16x8*)(hb + (ra ^ 64));
        f32x4 z = {0.f, 0.f, 0.f, 0.f};
        f32x4 ac[4];
        #pragma unroll
        for (int G = 0; G < 4; G++) {
            ac[G] = __builtin_amdgcn_mfma_f32_16x16x32_bf16(a0, bfr[G][0], z, 0, 0, 0);
            ac[G] = __builtin_amdgcn_mfma_f32_16x16x32_bf16(a1, bfr[G][1], ac[G], 0, 0, 0);
        }
        char* hw = (char*)hl[buf ^ 1];
        #pragma unroll
        for (int r = 0; r < 4; r++) {
            const bool live = s < Ls[r];
            const float xi = ac[0][r] + P[r].x;
            const float xf = ac[1][r] + P[r].y;
            const float xg = ac[2][r] + P[r].z;
            const float xo = ac[3][r] + P[r].w;
            const float iv = fast_sig(xi);
            const float fv = fast_sig(xf);
            const float gv = fast_tanh(xg);
            const float ov = fast_sig(xo);
            const float cn = fmaf(fv, cst[r], iv * gv);
            const float hv = ov * fast_tanh(cn);
            if (live) {
                cst[r] = cn;
                *op[r] = hv;
                op[r] += od;
                const int R = 4 * q + r;
                *(ushort*)(hw + R * 128 + ((2 * u) ^ ((R & 7) << 4))) = f2bf(hv);
            }
        }
        #pragma unroll
        for (int r = 0; r < 4; r++) {
            P[r] = *(const float4*)pp[r];           // in flight across raw barrier
            if (s + 3 < Ls[r]) pp[r] += pd;
        }
        lds_barrier();   // lgkmcnt(0) + s_barrier only; no vmcnt drain
    };

    for (int s = 0; s < maxS; s += 2) {
        body(s, P0, 0);
        body(s + 1, P1, 1);
    }

    // zero-fill masked region t in [L, T) per chain
    for (int ci = 0; ci < 16; ci++) {
        const int Lc = lengths[c0 + ci];
        float* ob = out + (size_t)(c0 + ci) * T * out_stride + dir * 64;
        for (int idx = tid; idx < (T - Lc) * 64; idx += 256) {
            int t = Lc + (idx >> 6);
            ob[(size_t)t * out_stride + (idx & 63)] = 0.f;
        }
    }
}

// ---------------- one-hot knowledge into wenc_n cols 128..139 ----------------
__global__ __launch_bounds__(256) void onehot_kernel(
    const int* __restrict__ knowledge, float* __restrict__ wenc_n)
{
    int idx = blockIdx.x * 256 + threadIdx.x;
    if (idx >= 96 * 512) return;
    int kn = knowledge[idx];
    float* row = wenc_n + (size_t)idx * 140 + 128;
    #pragma unroll
    for (int q = 0; q < 12; q++) row[q] = (q == kn) ? 1.f : 0.f;
}

// ---------------- header: pick last valid step + one-hot ----------------
__global__ __launch_bounds__(256) void build_hs_kernel(
    const float* __restrict__ h1_head, const int* __restrict__ l_hpu,
    const int* __restrict__ knowledge_header, float* __restrict__ wenc_hs)
{
    int b = blockIdx.x, u = blockIdx.y;
    int g = b * 16 + u;
    int tid = threadIdx.x;
    int L = l_hpu[g];
    if (tid < 128) {
        wenc_hs[(size_t)g * 132 + tid] = h1_head[((size_t)g * 8 + (L - 1)) * 128 + tid];
    } else if (tid < 132) {
        int kh = knowledge_header[g];
        wenc_hs[(size_t)g * 132 + tid] = ((tid - 128) == kh) ? 1.f : 0.f;
    }
}

__global__ __launch_bounds__(256) void build_hsob_kernel(
    const float* __restrict__ wenc_hs, const int* __restrict__ wc,
    const int* __restrict__ wn, float* __restrict__ hs_ob)
{
    int b = blockIdx.x, w = blockIdx.y;
    int tid = threadIdx.x;
    int col = (w < wn[b]) ? wc[b * 4 + w] : 0;
    if (tid < 132)
        hs_ob[((size_t)b * 4 + w)* 132 + tid] = wenc_hs[((size_t)b * 16 + col) * 132 + tid];
}

// ---------------- attention scores + softmax + context (per (b,w)) ----------------
__global__ __launch_bounds__(256) void att_softmax_cn_kernel(
    const float* __restrict__ attx, const float* __restrict__ hs_ob,
    const float* __restrict__ wenc_n, const int* __restrict__ l_n,
    float* __restrict__ c_n)
{
    int b = blockIdx.x, w = blockIdx.y;
    int tid = threadIdx.x;
    int L = l_n[b];
    __shared__ float q[132];
    __shared__ float sc[512];
    __shared__ float red[256];
    if (tid < 132) q[tid] = hs_ob[((size_t)b * 4 + w) * 132 + tid];
    __syncthreads();
    for (int t = tid; t < 512; t += 256) {
        float s = -1e30f;
        if (t < L) {
            const float* ax = attx + ((size_t)b * 512 + t) * 132;
            float s0 = 0.f, s1 = 0.f, s2 = 0.f, s3 = 0.f;
            #pragma unroll
            for (int d = 0; d < 132; d += 4) {
                s0 = fmaf(ax[d + 0], q[d + 0], s0);
                s1 = fmaf(ax[d + 1], q[d + 1], s1);
                s2 = fmaf(ax[d + 2], q[d + 2], s2);
                s3 = fmaf(ax[d + 3], q[d + 3], s3);
            }
            s = (s0 + s1) + (s2 + s3);
        }
        sc[t] = s;
    }
    __syncthreads();
    red[tid] = fmaxf(sc[tid], sc[tid + 256]);
    __syncthreads();
    for (int off = 128; off > 0; off >>= 1) {
        if (tid < off) red[tid] = fmaxf(red[tid], red[tid + off]);
        __syncthreads();
    }
    float m = red[0];
    __syncthreads();
    float ps = 0.f;
    for (int t = tid; t < 512; t += 256) {
        float e = (t < L) ? __expf(sc[t] - m) : 0.f;
        sc[t] = e;
        ps += e;
    }
    red[tid] = ps;
    __syncthreads();
    for (int off = 128; off > 0; off >>= 1) {
        if (tid < off) red[tid] += red[tid + off];
        __syncthreads();
    }
    float inv = 1.f / red[0];
    if (tid < 140) {
        float acc = 0.f;
        for (int t = 0; t < L; t++)
            acc = fmaf(sc[t], wenc_n[((size_t)b * 512 + t) * 140 + tid], acc);
        c_n[((size_t)b * 4 + w) * 140 + tid] = acc * inv;
    }
}

// ---------------- vec = [c_n@Wc.T+b | hs_ob@Whs.T+b | Wop[:,op]+b] ----------------
__global__ __launch_bounds__(384) void build_vec_kernel(
    const float* __restrict__ c_n, const float* __restrict__ hs_ob,
    const float* __restrict__ Wc_w, const float* __restrict__ Wc_b,
    const float* __restrict__ Whs_w, const float* __restrict__ Whs_b,
    const float* __restrict__ Wop_w, const float* __restrict__ Wop_b,
    const int* __restrict__ wn, const int* __restrict__ wo,
    float* __restrict__ vec)
{
    int b = blockIdx.x, w = blockIdx.y;
    int j = threadIdx.x;
    __shared__ float cn[140];
    __shared__ float hb[132];
    if (j < 140) cn[j] = c_n[((size_t)b * 4 + w) * 140 + j];
    else if (j < 272) hb[j - 140] = hs_ob[((size_t)b * 4 + w) * 132 + (j - 140)];
    __syncthreads();
    float acc;
    if (j < 128) {
        acc = Wc_b[j];
        const float* r = Wc_w + (size_t)j * 140;
        for (int d = 0; d < 140; d++) acc = fmaf(r[d], cn[d], acc);
    } else if (j < 256) {
        int jj = j - 128;
        acc = Whs_b[jj];
        const float* r = Whs_w + (size_t)jj * 132;
        for (int d = 0; d < 132; d++) acc = fmaf(r[d], hb[d], acc);
    } else {
        int jj = j - 256;
        int op = (w < wn[b]) ? wo[b * 4 + w] : 0;
        acc = Wop_b[jj] + Wop_w[jj * 4 + op];
    }
    vec[((size_t)b * 4 + w) * 384 + j] = acc;
}

// ---------------- final: out[b,w,t,:] = tanh(vpart+npart)@out2.T + b, masked ----------------
__global__ __launch_bounds__(256) void final_kernel(
    const float* __restrict__ vpart, const float* __restrict__ npart,
    const float* __restrict__ out2_w, const float* __restrict__ out2_b,
    const int* __restrict__ l_n, float* __restrict__ out)
{
    int b = blockIdx.y;
    int tid = threadIdx.x;
    int t = blockIdx.x * 256 + tid;
    __shared__ float vp[512];
    __shared__ float w2[256];
    w2[tid] = out2_w[tid];
    for (int i = tid; i < 512; i += 256) vp[i] = vpart[(size_t)b * 512 + i];
    __syncthreads();
    int L = l_n[b];
    float s[4][2];
    if (t < L) {
        float b0 = out2_b[0], b1 = out2_b[1];
        #pragma unroll
        for (int w = 0; w < 4; w++) { s[w][0] = b0; s[w][1] = b1; }
        const float4* np4 = (const float4*)(npart + ((size_t)b * 512 + t) * 128);
        for (int h4 = 0; h4 < 32; h4++) {
            float4 n = np4[h4];
            const float* nf = (const float*)&n;
            #pragma unroll
            for (int e = 0; e < 4; e++) {
                int h = h4 * 4 + e;
                float nv = nf[e];
                float w0 = w2[h], w1 = w2[128 + h];
                #pragma unroll
                for (int w = 0; w < 4; w++) {
                    float z = fast_tanh(vp[w * 128 + h] + nv);
                    s[w][0] = fmaf(z, w0, s[w][0]);
                    s[w][1] = fmaf(z, w1, s[w][1]);
                }
            }
        }
    } else {
        #pragma unroll
        for (int w = 0; w < 4; w++) { s[w][0] = NEGV; s[w][1] = NEGV; }
    }
    #pragma unroll
    for (int w = 0; w < 4; w++) {
        size_t o = (((size_t)b * 4 + w) * 512 + t) * 2;
        out[o + 0] = s[w][0];
        out[o + 1] = s[w][1];
    }
}

// ---------------------------------------------------------------------------
extern "C" void kernel_launch(void* const* d_in, const int* in_sizes, int n_in,
                              void* d_out, int out_size, void* d_ws, size_t ws_size,
                              hipStream_t stream)
{
    const float* wemb_n   = (const float*)d_in[0];
    const float* wemb_hpu = (const float*)d_in[1];
    const float* Wih_n0f = (const float*)d_in[2];
    const float* Whh_n0f = (const float*)d_in[3];
    const float* b_n0f   = (const float*)d_in[4];
    const float* Wih_n0b = (const float*)d_in[5];
    const float* Whh_n0b = (const float*)d_in[6];
    const float* b_n0b   = (const float*)d_in[7];
    const float* Wih_n1f = (const float*)d_in[8];
    const float* Whh_n1f = (const float*)d_in[9];
    const float* b_n1f   = (const float*)d_in[10];
    const float* Wih_n1b = (const float*)d_in[11];
    const float* Whh_n1b = (const float*)d_in[12];
    const float* b_n1b   = (const float*)d_in[13];
    const float* Wih_h0f = (const float*)d_in[14];
    const float* Whh_h0f = (const float*)d_in[15];
    const float* b_h0f   = (const float*)d_in[16];
    const float* Wih_h0b = (const float*)d_in[17];
    const float* Whh_h0b = (const float*)d_in[18];
    const float* b_h0b   = (const float*)d_in[19];
    const float* Wih_h1f = (const float*)d_in[20];
    const float* Whh_h1f = (const float*)d_in[21];
    const float* b_h1f   = (const float*)d_in[22];
    const float* Wih_h1b = (const float*)d_in[23];
    const float* Whh_h1b = (const float*)d_in[24];
    const float* b_h1b   = (const float*)d_in[25];
    const float* Watt_w  = (const float*)d_in[26];
    const float* Watt_b  = (const float*)d_in[27];
    const float* Wc_w    = (const float*)d_in[28];
    const float* Wc_b    = (const float*)d_in[29];
    const float* Whs_w   = (const float*)d_in[30];
    const float* Whs_b   = (const float*)d_in[31];
    const float* Wop_w   = (const float*)d_in[32];
    const float* Wop_b   = (const float*)d_in[33];
    const float* out1_w  = (const float*)d_in[34];
    const float* out1_b  = (const float*)d_in[35];
    const float* out2_w  = (const float*)d_in[36];
    const float* out2_b  = (const float*)d_in[37];
    const int* l_n   = (const int*)d_in[38];
    const int* l_hpu = (const int*)d_in[39];
    const int* wc    = (const int*)d_in[40];
    const int* wn    = (const int*)d_in[41];
    const int* wo    = (const int*)d_in[42];
    const int* knowledge        = (const int*)d_in[43];
    const int* knowledge_header = (const int*)d_in[44];

    float* ws = (float*)d_ws;
    // fp32 regions
    float* proj_f  = ws + 0;           // [0, 12582912)
    float* proj_b  = ws + 12582912;    // [12582912, 25165824)
    float* wenc0   = ws + 25165824;    // [25165824, 31457280)
    float* h_h0    = ws + 25165824;    // [25165824, 26738688)
    float* h1_head = ws + 26738688;    // [26738688, 28311552)
    float* wenc_n  = ws + 31457280;    // [31457280, 38338560)
    float* attx    = ws + 0;           // reuse proj area after header phase
    float* npart   = ws + 6488064;     // [6488064, 12779520)
    float* wenc_hs = ws + 38338560;    // [38338560, 38541312)
    float* hs_ob   = ws + 38541312;
    float* c_n     = ws + 38592000;
    float* vec     = ws + 38645760;
    float* vpart   = ws + 38793216;    // ends 38842368
    // bf16 / padded aliases (lifetime-disjoint with fp32 tenants)
    ushort* AbfQ0 = (ushort*)(ws + 25165824);  // wemb_n bf16
    ushort* AbfQ1 = (ushort*)(ws + 31457280);  // wenc0 bf16
    ushort* AbfH0 = (ushort*)(ws + 25165824);  // wemb_hpu bf16
    ushort* AbfH1 = (ushort*)(ws + 28311552);  // h_h0 bf16
    ushort* Wbf   = (ushort*)(ws + 38338560);  // per-layer Wih bf16
    ushort* wfrag = (ushort*)(ws + 38592000);  // Whh frags
    ushort* A_pad = (ushort*)(ws + 12779520);  // wenc_n padded bf16 [49152][192]
    ushort* Bp_att = (ushort*)(ws + 17500000); // Watt_w padded [256][192]
    ushort* Bp_out = (ushort*)(ws + 17530000); // out1_w[:,384:] padded [128][192]
    float*  bias_pad = ws + 17550000;          // Watt_b padded [256]
    float* outp    = (float*)d_out;

    dim3 blk(256);
    auto cast = [&](const float* in, ushort* out, int n) {
        cast_bf16_kernel<<<dim3(n / 2048), blk, 0, stream>>>(in, out, n);
    };
    auto mgemm = [&](const ushort* A, const ushort* B, const float* bias, float* C,
                     int M, int K) {
        gemm_mfma_kernel<<<dim3(2, M / 128), blk, 0, stream>>>(A, B, bias, C, M, K, 256, 256, 1);
    };

    prepack_whh_kernel<<<dim3(8), blk, 0, stream>>>(
        Whh_n0f, Whh_n0b, Whh_n1f, Whh_n1b, Whh_h0f, Whh_h0b, Whh_h1f, Whh_h1b, wfrag);

    // ---- question encoder, layer 0 (K=512) ----
    cast(wemb_n, AbfQ0, 96 * 512 * 512);
    cast(Wih_n0f, Wbf, 256 * 512);
    cast(Wih_n0b, Wbf + 256 * 512, 256 * 512);
    mgemm(AbfQ0, Wbf, b_n0f, proj_f, 96 * 512, 512);
    mgemm(AbfQ0, Wbf + 256 * 512, b_n0b, proj_b, 96 * 512, 512);
    lstm_scan_mfma16<<<dim3(6, 2), blk, 0, stream>>>(proj_f, proj_b,
        wfrag + 0 * 16384, wfrag + 1 * 16384, l_n, wenc0, 512, 128);

    // ---- question encoder, layer 1 (K=128) ----
    cast(wenc0, AbfQ1, 96 * 512 * 128);
    cast(Wih_n1f, Wbf, 256 * 128);
    cast(Wih_n1b, Wbf + 256 * 128, 256 * 128);
    mgemm(AbfQ1, Wbf, b_n1f, proj_f, 96 * 512, 128);
    mgemm(AbfQ1, Wbf + 256 * 128, b_n1b, proj_b, 96 * 512, 128);
    lstm_scan_mfma16<<<dim3(6, 2), blk, 0, stream>>>(proj_f, proj_b,
        wfrag + 2 * 16384, wfrag + 3 * 16384, l_n, wenc_n, 512, 140);
    onehot_kernel<<<dim3(192), blk, 0, stream>>>(knowledge, wenc_n);

    // ---- header encoder, layer 0 (K=512) ----
    cast(wemb_hpu, AbfH0, 1536 * 8 * 512);
    cast(Wih_h0f, Wbf, 256 * 512);
    cast(Wih_h0b, Wbf + 256 * 512, 256 * 512);
    mgemm(AbfH0, Wbf, b_h0f, proj_f, 1536 * 8, 512);
    mgemm(AbfH0, Wbf + 256 * 512, b_h0b, proj_b, 1536 * 8, 512);
    lstm_scan_mfma16<<<dim3(96, 2), blk, 0, stream>>>(proj_f, proj_b,
        wfrag + 4 * 16384, wfrag + 5 * 16384, l_hpu, h_h0, 8, 128);

    // ---- header encoder, layer 1 (K=128) ----
    cast(h_h0, AbfH1, 1536 * 8 * 128);
    cast(Wih_h1f, Wbf, 256 * 128);
    cast(Wih_h1b, Wbf + 256 * 128, 256 * 128);
    mgemm(AbfH1, Wbf, b_h1f, proj_f, 1536 * 8, 128);
    mgemm(AbfH1, Wbf + 256 * 128, b_h1b, proj_b, 1536 * 8, 128);
    lstm_scan_mfma16<<<dim3(96, 2), blk, 0, stream>>>(proj_f, proj_b,
        wfrag + 6 * 16384, wfrag + 7 * 16384, l_hpu, h1_head, 8, 128);
    build_hs_kernel<<<dim3(96, 16), blk, 0, stream>>>(h1_head, l_hpu, knowledge_header, wenc_hs);
    build_hsob_kernel<<<dim3(96, 4), blk, 0, stream>>>(wenc_hs, wc, wn, hs_ob);

    // ---- attention: pad wenc_n/Watt to K=192 bf16, MFMA GEMM ----
    pad_cast_a_kernel<<<dim3((49152 * 24 + 255) / 256), blk, 0, stream>>>(wenc_n, A_pad, 49152, 140);
    pad_cast_b_kernel<<<dim3(256), dim3(96), 0, stream>>>(Watt_w, Bp_att, 132, 140, 0);
    pad_bias_kernel<<<dim3(1), blk, 0, stream>>>(Watt_b, bias_pad, 132);
    pad_cast_b_kernel<<<dim3(128), dim3(96), 0, stream>>>(out1_w, Bp_out, 128, 524, 384);
    gemm_mfma_kernel<<<dim3(2, 384), blk, 0, stream>>>(
        A_pad, Bp_att, bias_pad, attx, 49152, 192, 132, 132, 0);
    att_softmax_cn_kernel<<<dim3(96, 4), blk, 0, stream>>>(attx, hs_ob, wenc_n, l_n, c_n);

    // ---- vec / split out1 ----
    build_vec_kernel<<<dim3(96, 4), dim3(384), 0, stream>>>(c_n, hs_ob, Wc_w, Wc_b,
                                                            Whs_w, Whs_b, Wop_w, Wop_b,
                                                            wn, wo, vec);
    gemm_bias_kernel<<<dim3(2, 6), blk, 0, stream>>>(vec, out1_w, out1_b, vpart,
                                                     384, 128, 384, 384, 524, 128);
    gemm_mfma_kernel<<<dim3(1, 384), blk, 0, stream>>>(
        A_pad, Bp_out, nullptr, npart, 49152, 192, 128, 128, 0);

    // ---- final ----
    final_kernel<<<dim3(2, 96), blk, 0, stream>>>(vpart, npart, out2_w, out2_b, l_n, outp);
}